// Round 18
// baseline (339.477 us; speedup 1.0000x reference)
//
#include <hip/hip_runtime.h>
#include <cfloat>
#include <math.h>

// Problem constants
#define N_TEXT  226
#define N_IMG   5400
#define N_TOKEN 5626
#define HEAD_STRIDE 31651876u   // N_TOKEN*N_TOKEN
#define TOTAL_ELEMS 126607504u  // 4 * HEAD_STRIDE
#define NA4  317869             // f4 slots in region A per head (226*5626/4)
#define NQB  57                 // aligned f4 slots covering cols [0,226) per row
#define NA_ALL (4 * NA4)        // 1271476
#define NB_ALL (4 * 5400 * NQB) // 1231200
#define GRID    256
#define THREADS 1024

// f32(1/15): XLA rewrites divide-by-constant into multiply-by-reciprocal.
#define RCP15 0x1.111112p-4f

typedef float f32x4 __attribute__((ext_vector_type(4)));

// Locked bit-exact arithmetic (verified r9/r11/r14/r16, absmax=0):
__device__ __forceinline__ float fq1(float x, float recip, float scale) {
    float q = rintf(__fmul_rn(x, recip));
    q = fminf(fmaxf(q, 0.0f), 15.0f);
    return __fmul_rn(q, scale);
}

// ---------------------------------------------------------------------------
// Per-tile ops (r16-validated masked aligned-f4 coverage), split into
// load / max / store so the persistent loop can software-pipeline them.
// ---------------------------------------------------------------------------
template <int BW, int NB, int R>
struct TileOps {
    static constexpr int NQ   = BW / 4 + 1;   // 51 / 38 / 31 / 26
    static constexpr int TOTQ = BW * NQ;

    static __device__ __forceinline__ unsigned baseOf(int local, int head) {
        const int bi = local / NB;
        const int bj = local - bi * NB;
        return (unsigned)head * HEAD_STRIDE
             + (unsigned)(N_TEXT + bi * BW) * N_TOKEN
             + (unsigned)(N_TEXT + bj * BW);
    }

    static __device__ __forceinline__ void load(const float* __restrict__ in,
                                                f32x4 (&buf)[R],
                                                unsigned base, int tid) {
        #pragma unroll
        for (int j = 0; j < R; ++j) {
            const int i = tid + j * THREADS;
            const int r = i / NQ;
            const int k = i - r * NQ;
            const unsigned rowbase = base + (unsigned)r * N_TOKEN;
            const int s = (int)(rowbase & 3u);        // 0 or 2
            const unsigned a0 = rowbase - s + (unsigned)(k << 2);
            const bool act = (i < TOTQ) && (a0 + 4u <= TOTAL_ELEMS);
            buf[j] = act ? *(const f32x4*)(in + a0) : (f32x4){0.f, 0.f, 0.f, 0.f};
        }
    }

    static __device__ __forceinline__ float maxOf(const f32x4 (&buf)[R],
                                                  unsigned base, int tid) {
        float m = 0.0f;                               // inputs are >= 0
        #pragma unroll
        for (int j = 0; j < R; ++j) {
            const int i = tid + j * THREADS;
            const int r = i / NQ;
            const int k = i - r * NQ;
            const unsigned rowbase = base + (unsigned)r * N_TOKEN;
            const int s = (int)(rowbase & 3u);
            const unsigned a0 = rowbase - s + (unsigned)(k << 2);
            if ((i < TOTQ) && (a0 + 4u <= TOTAL_ELEMS)) {
                const int c0 = (k << 2) - s;          // tile-rel col of v.x
                m = fmaxf(m, (c0 >= 0 && c0 < BW)         ? buf[j].x : 0.0f);
                m = fmaxf(m, (c0 + 1 >= 0 && c0 + 1 < BW) ? buf[j].y : 0.0f);
                m = fmaxf(m, (c0 + 2 < BW)                ? buf[j].z : 0.0f);
                m = fmaxf(m, (c0 + 3 < BW)                ? buf[j].w : 0.0f);
            }
        }
        return m;
    }

    static __device__ __forceinline__ void store(float* __restrict__ out,
                                                 const f32x4 (&buf)[R],
                                                 unsigned base, int tid,
                                                 float recip, float scale) {
        #pragma unroll
        for (int j = 0; j < R; ++j) {
            const int i = tid + j * THREADS;
            const int r = i / NQ;
            const int k = i - r * NQ;
            const unsigned rowbase = base + (unsigned)r * N_TOKEN;
            const int s = (int)(rowbase & 3u);
            const unsigned a0 = rowbase - s + (unsigned)(k << 2);
            if (i >= TOTQ || a0 + 4u > TOTAL_ELEMS) continue;
            const int c0 = (k << 2) - s;
            f32x4 v = buf[j];
            v.x = fq1(v.x, recip, scale);
            v.y = fq1(v.y, recip, scale);
            v.z = fq1(v.z, recip, scale);
            v.w = fq1(v.w, recip, scale);
            if (c0 >= 0 && c0 + 3 < BW) {
                *(f32x4*)(out + a0) = v;              // interior slot
            } else {                                  // edge: per-elem mask
                if (c0 >= 0 && c0 < BW)         out[a0]     = v.x;
                if (c0 + 1 >= 0 && c0 + 1 < BW) out[a0 + 1] = v.y;
                if (c0 + 2 < BW)                out[a0 + 2] = v.z;
                if (c0 + 3 < BW)                out[a0 + 3] = v.w;
            }
        }
    }
};

// ---------------------------------------------------------------------------
// Persistent per-head loop with double-buffered register tiles: issue tile
// t+1's loads BEFORE reducing tile t, so loads stay in flight across the
// barrier + store drain (the measured ~40% phase bubble of r16).
// ---------------------------------------------------------------------------
template <int BW, int NB, int R>
__device__ __forceinline__ void run_head(const float* __restrict__ in,
                                         float* __restrict__ out,
                                         int head, int wb, int tid,
                                         float (&sm)[2][16]) {
    using T = TileOps<BW, NB, R>;
    constexpr int NT = NB * NB;

    f32x4 A[R], B[R];
    int t = wb;
    unsigned baseCur = T::baseOf(t, head);
    T::load(in, A, baseCur, tid);
    bool curIsA = true;
    int it = 0;

    while (t < NT) {
        const int tn = t + 64;
        unsigned baseNext = 0;
        if (tn < NT) {                                // prefetch next tile
            baseNext = T::baseOf(tn, head);
            if (curIsA) T::load(in, B, baseNext, tid);
            else        T::load(in, A, baseNext, tid);
        }
        float m = curIsA ? T::maxOf(A, baseCur, tid)
                         : T::maxOf(B, baseCur, tid);
        #pragma unroll
        for (int o = 32; o > 0; o >>= 1)
            m = fmaxf(m, __shfl_xor(m, o));
        const int p = it & 1;                         // sm parity: no 2nd barrier
        if ((tid & 63) == 0) sm[p][tid >> 6] = m;
        __syncthreads();
        float delta = sm[p][0];
        #pragma unroll
        for (int w = 1; w < 16; ++w) delta = fmaxf(delta, sm[p][w]);

        const float scale = __fmul_rn(delta, RCP15);
        const float safe  = (scale == 0.0f) ? 1.0f : scale;
        const float recip = __fdiv_rn(1.0f, safe);

        if (curIsA) T::store(out, A, baseCur, tid, recip, scale);
        else        T::store(out, B, baseCur, tid, recip, scale);

        baseCur = baseNext;
        t = tn;
        curIsA = !curIsA;
        ++it;
    }
}

// ---------------------------------------------------------------------------
// Text copy (grid-stride epilogue over all GRID blocks; r16-validated masks).
// ---------------------------------------------------------------------------
__device__ __forceinline__ void text_copy(const float* __restrict__ in,
                                          float* __restrict__ out, int b) {
    const int tid0   = b * THREADS + threadIdx.x;
    const int stride = GRID * THREADS;

    for (int idx = tid0; idx < NA_ALL; idx += stride) {
        const int head = idx / NA4;
        const int rem  = idx - head * NA4;
        const size_t a = (size_t)head * HEAD_STRIDE + (size_t)rem * 4;
        *(f32x4*)(out + a) = *(const f32x4*)(in + a);
    }

    for (int idx = tid0; idx < NB_ALL; idx += stride) {
        const int head = idx / (5400 * NQB);
        const int rem  = idx - head * (5400 * NQB);
        const int row  = rem / NQB;
        const int k    = rem - row * NQB;
        const unsigned rowbase = (unsigned)head * HEAD_STRIDE
                               + (unsigned)(N_TEXT + row) * N_TOKEN;
        const int s = (int)(rowbase & 3u);            // 0 or 2
        const unsigned a0 = rowbase - s + (unsigned)(k << 2);
        const int c0 = (k << 2) - s;                  // text col of elem 0
        f32x4 v = *(const f32x4*)(in + a0);
        if (c0 >= 0 && c0 + 3 < N_TEXT) {
            *(f32x4*)(out + a0) = v;
        } else {
            if (c0 >= 0 && c0 < N_TEXT)         out[a0]     = v.x;
            if (c0 + 1 >= 0 && c0 + 1 < N_TEXT) out[a0 + 1] = v.y;
            if (c0 + 2 < N_TEXT)                out[a0 + 2] = v.z;
            if (c0 + 3 < N_TEXT)                out[a0 + 3] = v.w;
        }
    }
}

// ---------------------------------------------------------------------------
__global__ __launch_bounds__(THREADS)
__attribute__((amdgpu_waves_per_eu(4, 4)))   // pin 4 waves/EU -> 128 VGPR, no r17-style spill
void qam_persist(const float* __restrict__ in, float* __restrict__ out) {
    __shared__ float sm[2][16];
    const int b    = blockIdx.x;
    const int head = b >> 6;
    const int wb   = b & 63;
    const int tid  = threadIdx.x;
    switch (head) {
        case 0:  run_head<200, 27, 10>(in, out, 0, wb, tid, sm); break;
        case 1:  run_head<150, 36, 6> (in, out, 1, wb, tid, sm); break;
        case 2:  run_head<120, 45, 4> (in, out, 2, wb, tid, sm); break;
        default: run_head<100, 54, 3> (in, out, 3, wb, tid, sm); break;
    }
    text_copy(in, out, b);
}

extern "C" void kernel_launch(void* const* d_in, const int* in_sizes, int n_in,
                              void* d_out, int out_size, void* d_ws, size_t ws_size,
                              hipStream_t stream) {
    const float* x = (const float*)d_in[0];
    float* out     = (float*)d_out;
    qam_persist<<<GRID, THREADS, 0, stream>>>(x, out);
}

// Round 19
// 339.325 us; speedup vs baseline: 1.0004x; 1.0004x over previous
//
#include <hip/hip_runtime.h>
#include <cfloat>
#include <math.h>

// Problem constants
#define N_TEXT  226
#define N_IMG   5400
#define N_TOKEN 5626
#define HEAD_STRIDE 31651876u   // N_TOKEN*N_TOKEN
#define TOTAL_ELEMS 126607504u  // 4 * HEAD_STRIDE
#define NA4  317869             // f4 slots in region A per head (226*5626/4)
#define NQB  57                 // aligned f4 slots covering cols [0,226) per row
#define NA_ALL (4 * NA4)        // 1271476
#define NB_ALL (4 * 5400 * NQB) // 1231200
#define GRID    256
#define THREADS 1024

// f32(1/15): XLA rewrites divide-by-constant into multiply-by-reciprocal.
#define RCP15 0x1.111112p-4f

typedef float f32x4 __attribute__((ext_vector_type(4)));

// Locked bit-exact arithmetic (verified r9/r11/r14/r16, absmax=0):
__device__ __forceinline__ float fq1(float x, float recip, float scale) {
    float q = rintf(__fmul_rn(x, recip));
    q = fminf(fmaxf(q, 0.0f), 15.0f);
    return __fmul_rn(q, scale);
}

// ---------------------------------------------------------------------------
// Per-tile ops (r16-validated masked aligned-f4 coverage), split into
// load / max / store so the persistent loop can software-pipeline them.
// ---------------------------------------------------------------------------
template <int BW, int NB, int R>
struct TileOps {
    static constexpr int NQ   = BW / 4 + 1;   // 51 / 38 / 31 / 26
    static constexpr int TOTQ = BW * NQ;

    static __device__ __forceinline__ unsigned baseOf(int local, int head) {
        const int bi = local / NB;
        const int bj = local - bi * NB;
        return (unsigned)head * HEAD_STRIDE
             + (unsigned)(N_TEXT + bi * BW) * N_TOKEN
             + (unsigned)(N_TEXT + bj * BW);
    }

    static __device__ __forceinline__ void load(const float* __restrict__ in,
                                                f32x4 (&buf)[R],
                                                unsigned base, int tid) {
        #pragma unroll
        for (int j = 0; j < R; ++j) {
            const int i = tid + j * THREADS;
            const int r = i / NQ;
            const int k = i - r * NQ;
            const unsigned rowbase = base + (unsigned)r * N_TOKEN;
            const int s = (int)(rowbase & 3u);        // 0 or 2
            const unsigned a0 = rowbase - s + (unsigned)(k << 2);
            const bool act = (i < TOTQ) && (a0 + 4u <= TOTAL_ELEMS);
            buf[j] = act ? *(const f32x4*)(in + a0) : (f32x4){0.f, 0.f, 0.f, 0.f};
        }
    }

    static __device__ __forceinline__ float maxOf(const f32x4 (&buf)[R],
                                                  unsigned base, int tid) {
        float m = 0.0f;                               // inputs are >= 0
        #pragma unroll
        for (int j = 0; j < R; ++j) {
            const int i = tid + j * THREADS;
            const int r = i / NQ;
            const int k = i - r * NQ;
            const unsigned rowbase = base + (unsigned)r * N_TOKEN;
            const int s = (int)(rowbase & 3u);
            const unsigned a0 = rowbase - s + (unsigned)(k << 2);
            if ((i < TOTQ) && (a0 + 4u <= TOTAL_ELEMS)) {
                const int c0 = (k << 2) - s;          // tile-rel col of v.x
                m = fmaxf(m, (c0 >= 0 && c0 < BW)         ? buf[j].x : 0.0f);
                m = fmaxf(m, (c0 + 1 >= 0 && c0 + 1 < BW) ? buf[j].y : 0.0f);
                m = fmaxf(m, (c0 + 2 < BW)                ? buf[j].z : 0.0f);
                m = fmaxf(m, (c0 + 3 < BW)                ? buf[j].w : 0.0f);
            }
        }
        return m;
    }

    static __device__ __forceinline__ void store(float* __restrict__ out,
                                                 const f32x4 (&buf)[R],
                                                 unsigned base, int tid,
                                                 float recip, float scale) {
        #pragma unroll
        for (int j = 0; j < R; ++j) {
            const int i = tid + j * THREADS;
            const int r = i / NQ;
            const int k = i - r * NQ;
            const unsigned rowbase = base + (unsigned)r * N_TOKEN;
            const int s = (int)(rowbase & 3u);
            const unsigned a0 = rowbase - s + (unsigned)(k << 2);
            if (i >= TOTQ || a0 + 4u > TOTAL_ELEMS) continue;
            const int c0 = (k << 2) - s;
            f32x4 v = buf[j];
            v.x = fq1(v.x, recip, scale);
            v.y = fq1(v.y, recip, scale);
            v.z = fq1(v.z, recip, scale);
            v.w = fq1(v.w, recip, scale);
            if (c0 >= 0 && c0 + 3 < BW) {
                *(f32x4*)(out + a0) = v;              // interior slot
            } else {                                  // edge: per-elem mask
                if (c0 >= 0 && c0 < BW)         out[a0]     = v.x;
                if (c0 + 1 >= 0 && c0 + 1 < BW) out[a0 + 1] = v.y;
                if (c0 + 2 < BW)                out[a0 + 2] = v.z;
                if (c0 + 3 < BW)                out[a0 + 3] = v.w;
            }
        }
    }
};

// ---------------------------------------------------------------------------
// Persistent per-head loop with double-buffered register tiles: issue tile
// t+1's loads BEFORE reducing tile t, so loads stay in flight across the
// barrier + store drain (the measured ~40% phase bubble of r16).
// ---------------------------------------------------------------------------
template <int BW, int NB, int R>
__device__ __forceinline__ void run_head(const float* __restrict__ in,
                                         float* __restrict__ out,
                                         int head, int wb, int tid,
                                         float (&sm)[2][16]) {
    using T = TileOps<BW, NB, R>;
    constexpr int NT = NB * NB;

    f32x4 A[R], B[R];
    int t = wb;
    unsigned baseCur = T::baseOf(t, head);
    T::load(in, A, baseCur, tid);
    bool curIsA = true;
    int it = 0;

    while (t < NT) {
        const int tn = t + 64;
        unsigned baseNext = 0;
        if (tn < NT) {                                // prefetch next tile
            baseNext = T::baseOf(tn, head);
            if (curIsA) T::load(in, B, baseNext, tid);
            else        T::load(in, A, baseNext, tid);
        }
        float m = curIsA ? T::maxOf(A, baseCur, tid)
                         : T::maxOf(B, baseCur, tid);
        #pragma unroll
        for (int o = 32; o > 0; o >>= 1)
            m = fmaxf(m, __shfl_xor(m, o));
        const int p = it & 1;                         // sm parity: no 2nd barrier
        if ((tid & 63) == 0) sm[p][tid >> 6] = m;
        __syncthreads();
        float delta = sm[p][0];
        #pragma unroll
        for (int w = 1; w < 16; ++w) delta = fmaxf(delta, sm[p][w]);

        const float scale = __fmul_rn(delta, RCP15);
        const float safe  = (scale == 0.0f) ? 1.0f : scale;
        const float recip = __fdiv_rn(1.0f, safe);

        if (curIsA) T::store(out, A, baseCur, tid, recip, scale);
        else        T::store(out, B, baseCur, tid, recip, scale);

        baseCur = baseNext;
        t = tn;
        curIsA = !curIsA;
        ++it;
    }
}

// ---------------------------------------------------------------------------
// Text copy (grid-stride epilogue over all GRID blocks; r16-validated masks).
// ---------------------------------------------------------------------------
__device__ __forceinline__ void text_copy(const float* __restrict__ in,
                                          float* __restrict__ out, int b) {
    const int tid0   = b * THREADS + threadIdx.x;
    const int stride = GRID * THREADS;

    for (int idx = tid0; idx < NA_ALL; idx += stride) {
        const int head = idx / NA4;
        const int rem  = idx - head * NA4;
        const size_t a = (size_t)head * HEAD_STRIDE + (size_t)rem * 4;
        *(f32x4*)(out + a) = *(const f32x4*)(in + a);
    }

    for (int idx = tid0; idx < NB_ALL; idx += stride) {
        const int head = idx / (5400 * NQB);
        const int rem  = idx - head * (5400 * NQB);
        const int row  = rem / NQB;
        const int k    = rem - row * NQB;
        const unsigned rowbase = (unsigned)head * HEAD_STRIDE
                               + (unsigned)(N_TEXT + row) * N_TOKEN;
        const int s = (int)(rowbase & 3u);            // 0 or 2
        const unsigned a0 = rowbase - s + (unsigned)(k << 2);
        const int c0 = (k << 2) - s;                  // text col of elem 0
        f32x4 v = *(const f32x4*)(in + a0);
        if (c0 >= 0 && c0 + 3 < N_TEXT) {
            *(f32x4*)(out + a0) = v;
        } else {
            if (c0 >= 0 && c0 < N_TEXT)         out[a0]     = v.x;
            if (c0 + 1 >= 0 && c0 + 1 < N_TEXT) out[a0 + 1] = v.y;
            if (c0 + 2 < N_TEXT)                out[a0 + 2] = v.z;
            if (c0 + 3 < N_TEXT)                out[a0 + 3] = v.w;
        }
    }
}

// ---------------------------------------------------------------------------
// __launch_bounds__(1024, 4): 2nd arg = min waves per EU -> VGPR cap 512/4 =
// 128, enough for the worst-case 80-VGPR double-buffer payload (r17/r18 were
// compiled at 64 VGPR and spilled; this is the canonical HIP control).
// ---------------------------------------------------------------------------
__global__ __launch_bounds__(THREADS, 4)
void qam_persist(const float* __restrict__ in, float* __restrict__ out) {
    __shared__ float sm[2][16];
    const int b    = blockIdx.x;
    const int head = b >> 6;
    const int wb   = b & 63;
    const int tid  = threadIdx.x;
    switch (head) {
        case 0:  run_head<200, 27, 10>(in, out, 0, wb, tid, sm); break;
        case 1:  run_head<150, 36, 6> (in, out, 1, wb, tid, sm); break;
        case 2:  run_head<120, 45, 4> (in, out, 2, wb, tid, sm); break;
        default: run_head<100, 54, 3> (in, out, 3, wb, tid, sm); break;
    }
    text_copy(in, out, b);
}

extern "C" void kernel_launch(void* const* d_in, const int* in_sizes, int n_in,
                              void* d_out, int out_size, void* d_ws, size_t ws_size,
                              hipStream_t stream) {
    const float* x = (const float*)d_in[0];
    float* out     = (float*)d_out;
    qam_persist<<<GRID, THREADS, 0, stream>>>(x, out);
}

// Round 20
// 273.291 us; speedup vs baseline: 1.2422x; 1.2416x over previous
//
#include <hip/hip_runtime.h>
#include <cfloat>
#include <math.h>

// Problem constants
#define N_TEXT  226
#define N_IMG   5400
#define N_TOKEN 5626
#define HEAD_STRIDE 31651876u   // N_TOKEN*N_TOKEN
#define TOTAL_ELEMS 126607504u  // 4 * HEAD_STRIDE
#define NA4  317869             // f4 slots in region A per head (226*5626/4)
#define NQB  57                 // aligned f4 slots covering cols [0,226) per row
#define NA_ALL (4 * NA4)        // 1271476
#define NB_ALL (4 * 5400 * NQB) // 1231200
#define TEXTB 1024              // text-copy blocks (256 thr) in head-3 dispatch

// f32(1/15): XLA rewrites divide-by-constant into multiply-by-reciprocal.
#define RCP15 0x1.111112p-4f

typedef float f32x4 __attribute__((ext_vector_type(4)));

// Locked bit-exact arithmetic (verified r9/r11/r14/r16, absmax=0):
//   scale = fl32(delta*fl32(1/15)); safe = scale==0?1:scale;
//   recip = fl32(1/safe); q = clip(roundeven(fl32(x*recip)),0,15);
//   out = fl32(q*scale).
__device__ __forceinline__ float fq1(float x, float recip, float scale) {
    float q = rintf(__fmul_rn(x, recip));
    q = fminf(fmaxf(q, 0.0f), 15.0f);
    return __fmul_rn(q, scale);
}

// ---------------------------------------------------------------------------
// Fused per-tile quantization (r16-validated masked aligned-f4 coverage),
// parameterized by block size T and payload R so each head's dispatch keeps
// R*4 <= ~48 VGPR (no spill at the compiler's 64-VGPR envelope) and gets
// multiple blocks/CU for load/store phase overlap.
// ---------------------------------------------------------------------------
template <int BW, int NB, int HEAD, int T, int R>
__device__ __forceinline__ void tile_fused(const float* __restrict__ in,
                                           float* __restrict__ out,
                                           int local) {
    constexpr int NQ   = BW / 4 + 1;     // 51 / 38 / 31 / 26
    constexpr int TOTQ = BW * NQ;
    constexpr int W    = T / 64;

    const int bi = local / NB;
    const int bj = local - bi * NB;
    const unsigned base = (unsigned)HEAD * HEAD_STRIDE
                        + (unsigned)(N_TEXT + bi * BW) * N_TOKEN
                        + (unsigned)(N_TEXT + bj * BW);
    const int tid = threadIdx.x;

    // ---- load + max accumulate (registers) ----
    f32x4 vr[R];
    float m = 0.0f;                       // inputs are >= 0
    #pragma unroll
    for (int j = 0; j < R; ++j) {
        const int i = tid + j * T;
        const int r = i / NQ;             // compile-time divisor
        const int k = i - r * NQ;
        const unsigned rowbase = base + (unsigned)r * N_TOKEN;
        const int s = (int)(rowbase & 3u);            // 0 or 2
        const unsigned a0 = rowbase - s + (unsigned)(k << 2);
        const bool act = (i < TOTQ) && (a0 + 4u <= TOTAL_ELEMS);
        vr[j] = act ? *(const f32x4*)(in + a0) : (f32x4){0.f, 0.f, 0.f, 0.f};
        if (act) {
            const int c0 = (k << 2) - s;              // tile-rel col of v.x
            m = fmaxf(m, (c0 >= 0 && c0 < BW)         ? vr[j].x : 0.0f);
            m = fmaxf(m, (c0 + 1 >= 0 && c0 + 1 < BW) ? vr[j].y : 0.0f);
            m = fmaxf(m, (c0 + 2 < BW)                ? vr[j].z : 0.0f);
            m = fmaxf(m, (c0 + 3 < BW)                ? vr[j].w : 0.0f);
        }
    }

    // ---- block reduce ----
    #pragma unroll
    for (int o = 32; o > 0; o >>= 1)
        m = fmaxf(m, __shfl_xor(m, o));
    __shared__ float sm[W];
    if ((tid & 63) == 0) sm[tid >> 6] = m;
    __syncthreads();
    float delta = sm[0];
    #pragma unroll
    for (int w = 1; w < W; ++w) delta = fmaxf(delta, sm[w]);

    const float scale = __fmul_rn(delta, RCP15);
    const float safe  = (scale == 0.0f) ? 1.0f : scale;
    const float recip = __fdiv_rn(1.0f, safe);

    // ---- quantize registers + masked store ----
    #pragma unroll
    for (int j = 0; j < R; ++j) {
        const int i = tid + j * T;
        const int r = i / NQ;
        const int k = i - r * NQ;
        const unsigned rowbase = base + (unsigned)r * N_TOKEN;
        const int s = (int)(rowbase & 3u);
        const unsigned a0 = rowbase - s + (unsigned)(k << 2);
        if (i >= TOTQ || a0 + 4u > TOTAL_ELEMS) continue;
        const int c0 = (k << 2) - s;
        f32x4 v = vr[j];
        v.x = fq1(v.x, recip, scale);
        v.y = fq1(v.y, recip, scale);
        v.z = fq1(v.z, recip, scale);
        v.w = fq1(v.w, recip, scale);
        if (c0 >= 0 && c0 + 3 < BW) {
            *(f32x4*)(out + a0) = v;                  // interior slot
        } else {                                      // edge: per-elem mask
            if (c0 >= 0 && c0 < BW)         out[a0]     = v.x;
            if (c0 + 1 >= 0 && c0 + 1 < BW) out[a0 + 1] = v.y;
            if (c0 + 2 < BW)                out[a0 + 2] = v.z;  // c0+2>=0 always
            if (c0 + 3 < BW)                out[a0 + 3] = v.w;
        }
    }
}

// ---------------------------------------------------------------------------
// Per-head kernels (separate dispatches -> per-head block size).
// ---------------------------------------------------------------------------
__global__ __launch_bounds__(1024)
void k_h0(const float* __restrict__ in, float* __restrict__ out) {
    tile_fused<200, 27, 0, 1024, 10>(in, out, blockIdx.x);
}
__global__ __launch_bounds__(512)
void k_h1(const float* __restrict__ in, float* __restrict__ out) {
    tile_fused<150, 36, 1, 512, 12>(in, out, blockIdx.x);
}
__global__ __launch_bounds__(512)
void k_h2(const float* __restrict__ in, float* __restrict__ out) {
    tile_fused<120, 45, 2, 512, 8>(in, out, blockIdx.x);
}

// ---------------------------------------------------------------------------
// Text copy (grid-stride, r16-validated masks), 256-thread version.
// ---------------------------------------------------------------------------
__device__ __forceinline__ void text_copy(const float* __restrict__ in,
                                          float* __restrict__ out, int cb) {
    const int tid0   = cb * 256 + threadIdx.x;
    const int stride = TEXTB * 256;

    for (int idx = tid0; idx < NA_ALL; idx += stride) {
        const int head = idx / NA4;
        const int rem  = idx - head * NA4;
        const size_t a = (size_t)head * HEAD_STRIDE + (size_t)rem * 4;
        *(f32x4*)(out + a) = *(const f32x4*)(in + a);
    }

    for (int idx = tid0; idx < NB_ALL; idx += stride) {
        const int head = idx / (5400 * NQB);
        const int rem  = idx - head * (5400 * NQB);
        const int row  = rem / NQB;
        const int k    = rem - row * NQB;
        const unsigned rowbase = (unsigned)head * HEAD_STRIDE
                               + (unsigned)(N_TEXT + row) * N_TOKEN;
        const int s = (int)(rowbase & 3u);            // 0 or 2
        const unsigned a0 = rowbase - s + (unsigned)(k << 2);
        const int c0 = (k << 2) - s;                  // text col of elem 0
        f32x4 v = *(const f32x4*)(in + a0);
        if (c0 >= 0 && c0 + 3 < N_TEXT) {
            *(f32x4*)(out + a0) = v;
        } else {
            if (c0 >= 0 && c0 < N_TEXT)         out[a0]     = v.x;
            if (c0 + 1 >= 0 && c0 + 1 < N_TEXT) out[a0 + 1] = v.y;
            if (c0 + 2 < N_TEXT)                out[a0 + 2] = v.z;
            if (c0 + 3 < N_TEXT)                out[a0 + 3] = v.w;
        }
    }
}

__global__ __launch_bounds__(256)
void k_h3(const float* __restrict__ in, float* __restrict__ out) {
    const int b = blockIdx.x;
    if (b < 2916) tile_fused<100, 54, 3, 256, 11>(in, out, b);
    else          text_copy(in, out, b - 2916);
}

extern "C" void kernel_launch(void* const* d_in, const int* in_sizes, int n_in,
                              void* d_out, int out_size, void* d_ws, size_t ws_size,
                              hipStream_t stream) {
    const float* x = (const float*)d_in[0];
    float* out     = (float*)d_out;
    k_h0<<<729,          1024, 0, stream>>>(x, out);
    k_h1<<<1296,          512, 0, stream>>>(x, out);
    k_h2<<<2025,          512, 0, stream>>>(x, out);
    k_h3<<<2916 + TEXTB,  256, 0, stream>>>(x, out);
}

// Round 21
// 250.626 us; speedup vs baseline: 1.3545x; 1.0904x over previous
//
#include <hip/hip_runtime.h>
#include <cfloat>
#include <math.h>

// Problem constants
#define N_TEXT  226
#define N_IMG   5400
#define N_TOKEN 5626
#define HEAD_STRIDE 31651876u   // N_TOKEN*N_TOKEN
#define TOTAL_ELEMS 126607504u  // 4 * HEAD_STRIDE
#define NTILE 6966              // 27^2+36^2+45^2+54^2
#define TEXT_BLOCKS 995         // interleaved: every 8th block of grid 7961
#define GRIDSZ 7961             // 7961 - floor(7961/8) = 6966 tile blocks
#define NA4  317869             // f4 slots in region A per head (226*5626/4)
#define NQB  57                 // aligned f4 slots covering cols [0,226) per row
#define NA_ALL (4 * NA4)        // 1271476
#define NB_ALL (4 * 5400 * NQB) // 1231200

// f32(1/15): XLA rewrites divide-by-constant into multiply-by-reciprocal.
#define RCP15 0x1.111112p-4f

typedef float f32x4 __attribute__((ext_vector_type(4)));

// Locked bit-exact arithmetic (verified r9/r11/r14/r16, absmax=0):
//   scale = fl32(delta*fl32(1/15)); safe = scale==0?1:scale;
//   recip = fl32(1/safe); q = clip(roundeven(fl32(x*recip)),0,15);
//   out = fl32(q*scale).
__device__ __forceinline__ float fq1(float x, float recip, float scale) {
    float q = rintf(__fmul_rn(x, recip));
    q = fminf(fmaxf(q, 0.0f), 15.0f);
    return __fmul_rn(q, scale);
}

// ---------------------------------------------------------------------------
// Fused per-tile quantization (r16-validated, byte-identical): load tile into
// registers via masked aligned-f4, block-reduce max, quantize, masked store.
// ---------------------------------------------------------------------------
template <int BW, int NB, int R>
__device__ __forceinline__ void tile_fused(const float* __restrict__ in,
                                           float* __restrict__ out,
                                           int local, int head) {
    constexpr int NQ   = BW / 4 + 1;     // 51 / 38 / 31 / 26
    constexpr int TOTQ = BW * NQ;

    const int bi = local / NB;
    const int bj = local - bi * NB;
    const unsigned base = (unsigned)head * HEAD_STRIDE
                        + (unsigned)(N_TEXT + bi * BW) * N_TOKEN
                        + (unsigned)(N_TEXT + bj * BW);
    const int tid = threadIdx.x;

    // ---- load + max accumulate (registers) ----
    f32x4 vr[R];
    float m = 0.0f;                       // inputs are >= 0
    #pragma unroll
    for (int j = 0; j < R; ++j) {
        const int i = tid + j * 1024;
        const int r = i / NQ;             // compile-time divisor
        const int k = i - r * NQ;
        const unsigned rowbase = base + (unsigned)r * N_TOKEN;
        const int s = (int)(rowbase & 3u);            // 0 or 2
        const unsigned a0 = rowbase - s + (unsigned)(k << 2);
        const bool act = (i < TOTQ) && (a0 + 4u <= TOTAL_ELEMS);
        vr[j] = act ? *(const f32x4*)(in + a0) : (f32x4){0.f, 0.f, 0.f, 0.f};
        if (act) {
            const int c0 = (k << 2) - s;              // tile-rel col of v.x
            m = fmaxf(m, (c0 >= 0 && c0 < BW)         ? vr[j].x : 0.0f);
            m = fmaxf(m, (c0 + 1 >= 0 && c0 + 1 < BW) ? vr[j].y : 0.0f);
            m = fmaxf(m, (c0 + 2 < BW)                ? vr[j].z : 0.0f);
            m = fmaxf(m, (c0 + 3 < BW)                ? vr[j].w : 0.0f);
        }
    }

    // ---- block reduce (16 waves) ----
    #pragma unroll
    for (int o = 32; o > 0; o >>= 1)
        m = fmaxf(m, __shfl_xor(m, o));
    __shared__ float sm[16];
    if ((tid & 63) == 0) sm[tid >> 6] = m;
    __syncthreads();
    float delta = sm[0];
    #pragma unroll
    for (int w = 1; w < 16; ++w) delta = fmaxf(delta, sm[w]);

    const float scale = __fmul_rn(delta, RCP15);
    const float safe  = (scale == 0.0f) ? 1.0f : scale;
    const float recip = __fdiv_rn(1.0f, safe);

    // ---- quantize registers + masked store ----
    #pragma unroll
    for (int j = 0; j < R; ++j) {
        const int i = tid + j * 1024;
        const int r = i / NQ;
        const int k = i - r * NQ;
        const unsigned rowbase = base + (unsigned)r * N_TOKEN;
        const int s = (int)(rowbase & 3u);
        const unsigned a0 = rowbase - s + (unsigned)(k << 2);
        if (i >= TOTQ || a0 + 4u > TOTAL_ELEMS) continue;
        const int c0 = (k << 2) - s;
        f32x4 v = vr[j];
        v.x = fq1(v.x, recip, scale);
        v.y = fq1(v.y, recip, scale);
        v.z = fq1(v.z, recip, scale);
        v.w = fq1(v.w, recip, scale);
        if (c0 >= 0 && c0 + 3 < BW) {
            *(f32x4*)(out + a0) = v;                  // interior slot
        } else {                                      // edge: per-elem mask
            if (c0 >= 0 && c0 < BW)         out[a0]     = v.x;
            if (c0 + 1 >= 0 && c0 + 1 < BW) out[a0 + 1] = v.y;
            if (c0 + 2 < BW)                out[a0 + 2] = v.z;  // c0+2>=0 always
            if (c0 + 3 < BW)                out[a0 + 3] = v.w;
        }
    }
}

// ---------------------------------------------------------------------------
// Text copy (grid-stride, r16-validated masks).
// ---------------------------------------------------------------------------
__device__ __forceinline__ void text_copy(const float* __restrict__ in,
                                          float* __restrict__ out, int cb) {
    const int tid0   = cb * 1024 + threadIdx.x;
    const int stride = TEXT_BLOCKS * 1024;

    for (int idx = tid0; idx < NA_ALL; idx += stride) {
        const int head = idx / NA4;
        const int rem  = idx - head * NA4;
        const size_t a = (size_t)head * HEAD_STRIDE + (size_t)rem * 4;
        *(f32x4*)(out + a) = *(const f32x4*)(in + a);
    }

    for (int idx = tid0; idx < NB_ALL; idx += stride) {
        const int head = idx / (5400 * NQB);
        const int rem  = idx - head * (5400 * NQB);
        const int row  = rem / NQB;
        const int k    = rem - row * NQB;
        const unsigned rowbase = (unsigned)head * HEAD_STRIDE
                               + (unsigned)(N_TEXT + row) * N_TOKEN;
        const int s = (int)(rowbase & 3u);            // 0 or 2
        const unsigned a0 = rowbase - s + (unsigned)(k << 2);
        const int c0 = (k << 2) - s;                  // text col of elem 0
        f32x4 v = *(const f32x4*)(in + a0);
        if (c0 >= 0 && c0 + 3 < N_TEXT) {
            *(f32x4*)(out + a0) = v;
        } else {
            if (c0 >= 0 && c0 < N_TEXT)         out[a0]     = v.x;
            if (c0 + 1 >= 0 && c0 + 1 < N_TEXT) out[a0 + 1] = v.y;
            if (c0 + 2 < N_TEXT)                out[a0 + 2] = v.z;
            if (c0 + 3 < N_TEXT)                out[a0 + 3] = v.w;
        }
    }
}

// ---------------------------------------------------------------------------
// Grid interleave: every 8th block (b&7==7) is a pure-streaming text-copy
// block, spread through the grid to fill tile blocks' reduce/store bubbles
// (r16 had them as a tail). tile_idx = b - ((b+1)>>3); text_idx = b>>3.
// ---------------------------------------------------------------------------
__global__ __launch_bounds__(1024)
void qam_fused(const float* __restrict__ in, float* __restrict__ out) {
    const int b = blockIdx.x;
    if ((b & 7) == 7) {
        text_copy(in, out, b >> 3);
        return;
    }
    const int t = b - ((b + 1) >> 3);     // tile index 0..6965
    if (t < 729)        tile_fused<200, 27, 10>(in, out, t,        0);
    else if (t < 2025)  tile_fused<150, 36, 6> (in, out, t - 729,  1);
    else if (t < 4050)  tile_fused<120, 45, 4> (in, out, t - 2025, 2);
    else                tile_fused<100, 54, 3> (in, out, t - 4050, 3);
}

extern "C" void kernel_launch(void* const* d_in, const int* in_sizes, int n_in,
                              void* d_out, int out_size, void* d_ws, size_t ws_size,
                              hipStream_t stream) {
    const float* x = (const float*)d_in[0];
    float* out     = (float*)d_out;
    qam_fused<<<GRIDSZ, 1024, 0, stream>>>(x, out);
}